// Round 7
// baseline (233.887 us; speedup 1.0000x reference)
//
#include <hip/hip_runtime.h>
#include <stdint.h>

// WaveletLayer fused kernel (fp32): db2 DWT (symmetric ext) -> scale cD by
// weight[0] -> db2 IDWT -> leaky_relu(0.01).
//
// R8 structure: controlled A/B against R4 (best so far, ~79 us kernel).
// IDENTICAL to R4 (one wave = 2 rows/iter, grid-stride, 2048 blocks, cached
// loads, plain stores) EXCEPT the halo mechanism: R3-R7 fetched the 2-float
// halos via __shfl_up/down, which lower to ds_bpermute_b32 -> every row's
// compute chain was load -> vmcnt wait -> 4x bpermute -> lgkmcnt wait ->
// compute. That LDS round-trip + second waitcnt per row is the one serial
// feature shared by all flat-at-~78us variants (R4-R7 proved MLP depth,
// cache hints, and SW pipelining all do nothing; VALUBusy 14%, HBM 30%,
// no pipe saturated -> an unmeasured serializer).
// R8 loads the halos directly from global as dwordx2: the same cache lines
// the neighbor lanes fetch, so L1/L2 absorb the +16 B/lane (zero extra HBM
// traffic). Boundary reflection = branchless ADDRESS select + value swap
// via cndmask. Kernel now has ZERO LDS ops, zero lgkm waits, no divergence.
//
// Halo address algebra (verified against R2-R7's shfl+reflection):
//   interior lane: hl = (x[col-2], x[col-1])  @ cb-2
//                  hr = (x[col+8], x[col+9])  @ cb+8
//   lane 0:  needs (xl0,xl1) = (x[1], x[0])   -> load @ rb   = (x0,x1), swap
//   lane 63: needs (xr0,xr1) = (x[511],x[510])-> load @ rb+510 = (x510,x511), swap
//
// Index algebra (harness-verified R2-R7):
//   cA[i] = DL3*x[2i-2] + DL2*x[2i-1] + DL1*x[2i] + DL0*x[2i+1]  (interior)
//   even j: z = RL2*A[i] + RL0*A[i+1] + RH2*D[i] + RH0*D[i+1],  i=j/2
//   odd  j: z = RL3*A[i] + RL1*A[i+1] + RH3*D[i] + RH1*D[i+1]
//   with D = weight[0] * cD.
// Lane t computes pairs i = 4t..4t+4 and outputs j = 8t..8t+7 of each row.

#define N 512

typedef float f4v __attribute__((ext_vector_type(4)));
typedef float f2v __attribute__((ext_vector_type(2)));

__device__ __forceinline__ void row_compute(
    const f4v va, const f4v vb,
    const float xl0, const float xl1, const float xr0, const float xr1,
    const f4v wv, const float w4,
    f4v& oa, f4v& ob)
{
    constexpr float DL0 = -0.12940952255092145f, DL1 = 0.22414386804185735f,
                    DL2 =  0.836516303737469f,   DL3 = 0.48296291314469025f;
    constexpr float DH0 = -0.48296291314469025f, DH1 = 0.836516303737469f,
                    DH2 = -0.22414386804185735f, DH3 = -0.12940952255092145f;
    constexpr float RL0 =  0.48296291314469025f, RL1 = 0.836516303737469f,
                    RL2 =  0.22414386804185735f, RL3 = -0.12940952255092145f;
    constexpr float RH0 = -0.12940952255092145f, RH1 = -0.22414386804185735f,
                    RH2 =  0.836516303737469f,   RH3 = -0.48296291314469025f;

    float A0 = DL3*xl0  + DL2*xl1  + DL1*va.x + DL0*va.y;
    float D0 = DH3*xl0  + DH2*xl1  + DH1*va.x + DH0*va.y;
    float A1 = DL3*va.x + DL2*va.y + DL1*va.z + DL0*va.w;
    float D1 = DH3*va.x + DH2*va.y + DH1*va.z + DH0*va.w;
    float A2 = DL3*va.z + DL2*va.w + DL1*vb.x + DL0*vb.y;
    float D2 = DH3*va.z + DH2*va.w + DH1*vb.x + DH0*vb.y;
    float A3 = DL3*vb.x + DL2*vb.y + DL1*vb.z + DL0*vb.w;
    float D3 = DH3*vb.x + DH2*vb.y + DH1*vb.z + DH0*vb.w;
    float A4 = DL3*vb.z + DL2*vb.w + DL1*xr0  + DL0*xr1;
    float D4 = DH3*vb.z + DH2*vb.w + DH1*xr0  + DH0*xr1;

    D0 *= wv.x; D1 *= wv.y; D2 *= wv.z; D3 *= wv.w; D4 *= w4;

    float z0 = RL2*A0 + RL0*A1 + RH2*D0 + RH0*D1;
    float z1 = RL3*A0 + RL1*A1 + RH3*D0 + RH1*D1;
    float z2 = RL2*A1 + RL0*A2 + RH2*D1 + RH0*D2;
    float z3 = RL3*A1 + RL1*A2 + RH3*D1 + RH1*D2;
    float z4 = RL2*A2 + RL0*A3 + RH2*D2 + RH0*D3;
    float z5 = RL3*A2 + RL1*A3 + RH3*D2 + RH1*D3;
    float z6 = RL2*A3 + RL0*A4 + RH2*D3 + RH0*D4;
    float z7 = RL3*A3 + RL1*A4 + RH3*D3 + RH1*D4;

    oa.x = fmaxf(z0, 0.f) + 0.01f * fminf(z0, 0.f);
    oa.y = fmaxf(z1, 0.f) + 0.01f * fminf(z1, 0.f);
    oa.z = fmaxf(z2, 0.f) + 0.01f * fminf(z2, 0.f);
    oa.w = fmaxf(z3, 0.f) + 0.01f * fminf(z3, 0.f);
    ob.x = fmaxf(z4, 0.f) + 0.01f * fminf(z4, 0.f);
    ob.y = fmaxf(z5, 0.f) + 0.01f * fminf(z5, 0.f);
    ob.z = fmaxf(z6, 0.f) + 0.01f * fminf(z6, 0.f);
    ob.w = fmaxf(z7, 0.f) + 0.01f * fminf(z7, 0.f);
}

__global__ __launch_bounds__(256) void wavelet_kernel(
    const float* __restrict__ x,
    const float* __restrict__ w,
    float* __restrict__ out,
    int nrows)
{
    const int lane = threadIdx.x & 63;
    const int wid  = threadIdx.x >> 6;

    // Per-lane weights: lane t scales pairs i = 4t .. 4t+4.
    const f4v  wv = *(const f4v*)(w + 4 * lane);
    const float w4 = w[4 * lane + 4];

    const bool l0  = (lane == 0);
    const bool l63 = (lane == 63);
    const size_t co = (size_t)lane << 3;          // owned-col offset in a row

    const int pairs = nrows >> 1;                 // nrows even (B=65536)
    const int pstep = (int)gridDim.x * 4;

    for (int p = (int)blockIdx.x * 4 + wid; p < pairs; p += pstep) {
        const size_t rb0 = ((size_t)p * 2) * N;   // row bases
        const size_t rb1 = rb0 + N;
        const size_t cb0 = rb0 + co;
        const size_t cb1 = rb1 + co;

        // halo addresses: branchless select (reflection at lane 0 / 63)
        const size_t hl0a = l0  ? rb0       : cb0 - 2;
        const size_t hr0a = l63 ? rb0 + 510 : cb0 + 8;
        const size_t hl1a = l0  ? rb1       : cb1 - 2;
        const size_t hr1a = l63 ? rb1 + 510 : cb1 + 8;

        // issue everything before any use; no LDS, no lgkm dependency
        f4v va0 = *(const f4v*)(x + cb0);
        f4v vb0 = *(const f4v*)(x + cb0 + 4);
        f2v hl0 = *(const f2v*)(x + hl0a);
        f2v hr0 = *(const f2v*)(x + hr0a);
        f4v va1 = *(const f4v*)(x + cb1);
        f4v vb1 = *(const f4v*)(x + cb1 + 4);
        f2v hl1 = *(const f2v*)(x + hl1a);
        f2v hr1 = *(const f2v*)(x + hr1a);

        // boundary lanes loaded the pair in reversed order -> cndmask swap
        const float xl00 = l0  ? hl0.y : hl0.x;
        const float xl01 = l0  ? hl0.x : hl0.y;
        const float xr00 = l63 ? hr0.y : hr0.x;
        const float xr01 = l63 ? hr0.x : hr0.y;
        const float xl10 = l0  ? hl1.y : hl1.x;
        const float xl11 = l0  ? hl1.x : hl1.y;
        const float xr10 = l63 ? hr1.y : hr1.x;
        const float xr11 = l63 ? hr1.x : hr1.y;

        f4v oa0, ob0, oa1, ob1;
        row_compute(va0, vb0, xl00, xl01, xr00, xr01, wv, w4, oa0, ob0);
        row_compute(va1, vb1, xl10, xl11, xr10, xr11, wv, w4, oa1, ob1);

        // plain (cached) stores — R4's policy, best measured
        *(f4v*)(out + cb0)     = oa0;
        *(f4v*)(out + cb0 + 4) = ob0;
        *(f4v*)(out + cb1)     = oa1;
        *(f4v*)(out + cb1 + 4) = ob1;
    }
}

extern "C" void kernel_launch(void* const* d_in, const int* in_sizes, int n_in,
                              void* d_out, int out_size, void* d_ws, size_t ws_size,
                              hipStream_t stream) {
    const float* x = (const float*)d_in[0];
    const float* w = (const float*)d_in[1];
    float* out = (float*)d_out;

    const int nrows = in_sizes[0] / N;          // element count / row length
    const int pairs = nrows >> 1;
    int blocks = (pairs + 3) / 4;               // 4 row-pairs per block-iter
    if (blocks > 2048) blocks = 2048;           // grid-stride the rest
    if (blocks < 1) blocks = 1;
    wavelet_kernel<<<blocks, 256, 0, stream>>>(x, w, out, nrows);
}